// Round 10
// baseline (181.679 us; speedup 1.0000x reference)
//
#include <hip/hip_runtime.h>

typedef unsigned short u16;
typedef unsigned int u32;

#define NB 4
#define NN 512
#define ND 256
#define NH 256
#define TI 2

typedef __attribute__((ext_vector_type(8))) short short8;
typedef __attribute__((ext_vector_type(4))) float f32x4;

__device__ __forceinline__ short bf(float f) {
    u32 t; __builtin_memcpy(&t, &f, 4);
    u32 r = (t + 0x7FFFu + ((t >> 16) & 1u)) >> 16;
    return (short)(u16)r;
}
__device__ __forceinline__ float blo(u32 u) {
    u32 t = u << 16; float f; __builtin_memcpy(&f, &t, 4); return f;
}
__device__ __forceinline__ float bhi(u32 u) {
    u32 t = u & 0xFFFF0000u; float f; __builtin_memcpy(&f, &t, 4); return f;
}

__device__ __forceinline__ float waveReduceSum(float v) {
#pragma unroll
    for (int o = 32; o > 0; o >>= 1) v += __shfl_down(v, o);
    return v;
}

// block-wide reduce of 4 values across 8 waves (512 threads)
__device__ __forceinline__ float4 blockReduce4(float4 v, float4* red4b, bool ismax) {
#pragma unroll
    for (int o = 32; o > 0; o >>= 1) {
        float4 t;
        t.x = __shfl_down(v.x, o); t.y = __shfl_down(v.y, o);
        t.z = __shfl_down(v.z, o); t.w = __shfl_down(v.w, o);
        if (ismax) {
            v.x = fmaxf(v.x, t.x); v.y = fmaxf(v.y, t.y);
            v.z = fmaxf(v.z, t.z); v.w = fmaxf(v.w, t.w);
        } else {
            v.x += t.x; v.y += t.y; v.z += t.z; v.w += t.w;
        }
    }
    int wid = threadIdx.x >> 6;
    __syncthreads();
    if ((threadIdx.x & 63) == 0) red4b[wid] = v;
    __syncthreads();
    float4 r = red4b[0];
#pragma unroll
    for (int w = 1; w < 8; ++w) {
        float4 u = red4b[w];
        if (ismax) {
            r.x = fmaxf(r.x, u.x); r.y = fmaxf(r.y, u.y);
            r.z = fmaxf(r.z, u.z); r.w = fmaxf(r.w, u.w);
        } else {
            r.x += u.x; r.y += u.y; r.z += u.z; r.w += u.w;
        }
    }
    return r;
}

// ---------------- K1: q/k/v projections via bf16 MFMA (inline cvt) + Wo^T ----------------
// grid (32, 49), 256 thr. y<48: MFMA jobs. y==48: Wo transpose -> packed bf16.
// q fp32 [row][h]; k -> kp u16 [b][h>>1][j][h&1]; v -> vp u16 [row][h]; Wo^T -> wop u16 [d>>1][o][d&1].
__global__ __launch_bounds__(256) void qkv_mfma(
    const float* __restrict__ x,
    const float* __restrict__ Wq, const float* __restrict__ bq,
    const float* __restrict__ Wk, const float* __restrict__ bk,
    const float* __restrict__ Wv, const float* __restrict__ bv,
    const float* __restrict__ Wo,
    float* __restrict__ q, u16* __restrict__ kp, u16* __restrict__ vp,
    u16* __restrict__ wop)
{
    const int tid = threadIdx.x;
    if (blockIdx.y == 48) {
        __shared__ float t[32][33];
        const int tx = tid & 31, ty = tid >> 5;
#pragma unroll
        for (int tt2 = 0; tt2 < 2; ++tt2) {
            const int tile = blockIdx.x * 2 + tt2;    // 0..63
            const int bx = tile & 7, by = tile >> 3;
            __syncthreads();
#pragma unroll
            for (int k = 0; k < 4; ++k)
                t[ty + 8 * k][tx] = Wo[(size_t)(by * 32 + ty + 8 * k) * 256 + bx * 32 + tx];
            __syncthreads();
#pragma unroll
            for (int k = 0; k < 4; ++k) {
                const int d = bx * 32 + ty + 8 * k, o = by * 32 + tx;
                wop[(size_t)(d >> 1) * 512 + 2 * o + (d & 1)] = (u16)bf(t[tx][ty + 8 * k]);
            }
        }
        return;
    }

    const int lane = tid & 63, wave = tid >> 6;
    const int r0 = blockIdx.x * 64 + wave * 16;
    const int out0 = blockIdx.y * 16;                  // 0..767
    const int which = blockIdx.y >> 4;
    const float* W   = (which == 0) ? Wq : (which == 1) ? Wk : Wv;
    const float* bia = (which == 0) ? bq : (which == 1) ? bk : bv;

    const int m = lane & 15, koff = (lane >> 4) * 8;
    const float* Ap = x + (size_t)(r0 + m) * 256 + koff;
    const float* Bp = W + (size_t)((out0 & 255) + m) * 256 + koff;

    f32x4 acc = {0.f, 0.f, 0.f, 0.f};
#pragma unroll
    for (int kb = 0; kb < 8; ++kb) {
        float4 a0 = *(const float4*)(Ap + kb * 32);
        float4 a1 = *(const float4*)(Ap + kb * 32 + 4);
        float4 b0 = *(const float4*)(Bp + kb * 32);
        float4 b1 = *(const float4*)(Bp + kb * 32 + 4);
        short8 af, bf8;
        af[0] = bf(a0.x); af[1] = bf(a0.y); af[2] = bf(a0.z); af[3] = bf(a0.w);
        af[4] = bf(a1.x); af[5] = bf(a1.y); af[6] = bf(a1.z); af[7] = bf(a1.w);
        bf8[0] = bf(b0.x); bf8[1] = bf(b0.y); bf8[2] = bf(b0.z); bf8[3] = bf(b0.w);
        bf8[4] = bf(b1.x); bf8[5] = bf(b1.y); bf8[6] = bf(b1.z); bf8[7] = bf(b1.w);
        acc = __builtin_amdgcn_mfma_f32_16x16x32_bf16(af, bf8, acc, 0, 0, 0);
    }

    const int oc = (out0 + m) & 255;          // D col = lane&15
    const float bias = bia[oc];
    const int rbase = r0 + (lane >> 4) * 4;   // D row = (lane>>4)*4 + reg
#pragma unroll
    for (int reg = 0; reg < 4; ++reg) {
        int R = rbase + reg;
        float val = acc[reg] + bias;
        if (which == 0) {
            q[(size_t)R * 256 + oc] = val;
        } else if (which == 1) {
            const int b_ = R >> 9, n = R & 511;
            kp[((size_t)(b_ * 128 + (oc >> 1)) * 512 + n) * 2 + (oc & 1)] = (u16)bf(val);
        } else {
            vp[(size_t)R * 256 + oc] = (u16)bf(val);
        }
    }
}

// ---------------- K2: fused attention, TI=2 rows, 512 threads, 1024 blocks ----------------
__global__ __launch_bounds__(512) void fused_kernel(
    const float* __restrict__ x, const float* __restrict__ area, const float* __restrict__ co,
    const float* __restrict__ We1, const float* __restrict__ be1,
    const float* __restrict__ We2, const float* __restrict__ be2,
    const u32* __restrict__ wop32, const float* __restrict__ bo,
    const float* __restrict__ g_ot, const float* __restrict__ b_ot,
    const float* __restrict__ g1, const float* __restrict__ b1,
    const float* __restrict__ g2, const float* __restrict__ b2,
    const float* __restrict__ q, const u32* __restrict__ kp32, const u32* __restrict__ vp32,
    float* __restrict__ out)
{
    const int tid = threadIdx.x;
    const int b = blockIdx.x >> 8;
    const int i0 = (blockIdx.x & 255) << 1;
    const int lane = tid & 63, w = tid >> 6;

    __shared__ float histS[512], histB[512], hist2S[512], hist2B[512];
    __shared__ float srow[1024];
    __shared__ float4 red4b[8];
    __shared__ float sBaseS[2], sBaseB[2], redA[8], redB[8];

    const float be2f = be2[0];

    // ---- gate: zero hist, scatter one hinge per thread, reduce always-active bases ----
    histS[tid] = 0.f; histB[tid] = 0.f;
    __syncthreads();
    {
        const int s = tid >> 8, h = tid & 255;             // set s (wave-uniform: waves 0-3 / 4-7)
        const float a = area[b * NN + i0 + s];
        float baS = 0.f, baB = 0.f;
        const float w10 = We1[2 * h], w11 = We1[2 * h + 1];
        const float w2v = We2[h], be1v = be1[h];
        const float al = fmaf(a, w10, be1v);
        const float sl = w11 * w2v, bb = al * w2v;
        if (w11 == 0.f) {
            if (al > 0.f) baB += bb;
        } else {
            float tt = -al / w11;
            if (w11 > 0.f) {
                if (tt <= 0.f)      { baS += sl; baB += bb; }
                else if (tt < 1.f) {
                    int u = (int)(tt * 256.f); u = u > 255 ? 255 : u;
                    atomicAdd(&histS[s * 256 + u], sl);
                    atomicAdd(&histB[s * 256 + u], bb);
                }
            } else {
                if (tt >= 1.f)      { baS += sl; baB += bb; }
                else if (tt > 0.f) {
                    baS += sl; baB += bb;
                    int u = (int)(tt * 256.f); u = u > 255 ? 255 : u;
                    atomicAdd(&histS[s * 256 + u], -sl);
                    atomicAdd(&histB[s * 256 + u], -bb);
                }
            }
        }
        float rS = waveReduceSum(baS), rB = waveReduceSum(baB);
        if (lane == 0) { redA[w] = rS; redB[w] = rB; }
    }
    __syncthreads();
    if (tid < 2) {
        sBaseS[tid] = redA[4 * tid] + redA[4 * tid + 1] + redA[4 * tid + 2] + redA[4 * tid + 3];
        sBaseB[tid] = redB[4 * tid] + redB[4 * tid + 1] + redB[4 * tid + 2] + redB[4 * tid + 3];
    }

    // ---- inclusive scan over 256 buckets x 2 sets (8 stages, ping-pong) ----
    {
        float* sa = histS; float* sb = histB; float* da = hist2S; float* db = hist2B;
        const int col = tid & 255, s2 = tid >> 8;
        for (int off = 1; off < 256; off <<= 1) {
            const int i1 = s2 * 256 + col;
            float v1a = sa[i1], v1b = sb[i1];
            if (col >= off) { v1a += sa[i1 - off]; v1b += sb[i1 - off]; }
            da[i1] = v1a; db[i1] = v1b;
            __syncthreads();
            float* t = sa; sa = da; da = t;
            t = sb; sb = db; db = t;
        }
        // 8 stages (even) -> scanned tables end in histS/histB
    }

    // ---- QK dot (j = tid) + gate + score; k as packed bf16 pairs along h ----
    float sA[TI];
    {
        const u32* kt = kp32 + (size_t)b * 128 * 512 + tid;
        const float* qb_ = q + (size_t)(b * NN + i0) * NH;
        float dot[TI] = {0.f, 0.f};
        for (int h = 0; h < 256; h += 4) {   // 64 iters, 2 u32 loads each
            const int h2 = h >> 1;
            u32 ka = kt[(size_t)h2 * 512];
            u32 kb = kt[(size_t)(h2 + 1) * 512];
            float k0 = blo(ka), k1 = bhi(ka), k2 = blo(kb), k3 = bhi(kb);
#pragma unroll
            for (int ti = 0; ti < TI; ++ti) {
                float4 qv = *(const float4*)&qb_[ti * 256 + h];  // wave-uniform -> s_load
                dot[ti] += qv.x * k0 + qv.y * k1 + qv.z * k2 + qv.w * k3;
            }
        }
#pragma unroll
        for (int ti = 0; ti < TI; ++ti) {
            float c = co[(size_t)(i0 + ti) * NN + tid];
            int u = (int)(c * 256.f); u = u > 255 ? 255 : u;
            float S = sBaseS[ti] + histS[ti * 256 + u];
            float B = sBaseB[ti] + histB[ti * 256 + u];
            float e = fmaf(c, S, B) + be2f;
            float ew = 1.f / (1.f + __expf(-e));
            sA[ti] = dot[ti] * 0.0625f * ew;
        }
    }

    // ---- softmax over j ----
    {
        float4 m4 = make_float4(sA[0], sA[1], -3e38f, -3e38f);
        m4 = blockReduce4(m4, red4b, true);
        float eA[TI];
        float4 s4 = make_float4(0.f, 0.f, 0.f, 0.f);
#pragma unroll
        for (int ti = 0; ti < TI; ++ti) {
            eA[ti] = __expf(sA[ti] - ((const float*)&m4)[ti]);
            ((float*)&s4)[ti] = eA[ti];
        }
        s4 = blockReduce4(s4, red4b, false);
#pragma unroll
        for (int ti = 0; ti < TI; ++ti)
            srow[ti * 512 + tid] = eA[ti] * (1.f / ((const float*)&s4)[ti]);
        __syncthreads();
    }

    // ---- PV: thread = (h-pair h2, j-quarter qtr); v packed bf16 pairs along h ----
    {
        const int h2 = tid & 127, qtr = tid >> 7;
        float a0[TI] = {0.f, 0.f};   // h = 2*h2
        float a1[TI] = {0.f, 0.f};   // h = 2*h2+1
        const u32* vp_ = vp32 + (size_t)b * 512 * 128 + h2;
        const float4* s4p = (const float4*)srow;
        for (int j4 = qtr * 32; j4 < qtr * 32 + 32; ++j4) {
            const int jj = 4 * j4;
            u32 va = vp_[(size_t)(jj + 0) * 128];
            u32 vb = vp_[(size_t)(jj + 1) * 128];
            u32 vc = vp_[(size_t)(jj + 2) * 128];
            u32 vd = vp_[(size_t)(jj + 3) * 128];
            float la = blo(va), ha = bhi(va), lb = blo(vb), hb = bhi(vb);
            float lc = blo(vc), hc = bhi(vc), ld = blo(vd), hd = bhi(vd);
#pragma unroll
            for (int ti = 0; ti < TI; ++ti) {
                float4 p4 = s4p[ti * 128 + j4];  // wave-uniform LDS broadcast
                a0[ti] += p4.x * la + p4.y * lb + p4.z * lc + p4.w * ld;
                a1[ti] += p4.x * ha + p4.y * hb + p4.z * hc + p4.w * hd;
            }
        }
        float2* bq_ = (float2*)((qtr == 0) ? histS : (qtr == 1) ? histB : (qtr == 2) ? hist2S : hist2B);
#pragma unroll
        for (int ti = 0; ti < TI; ++ti) bq_[ti * 128 + h2] = make_float2(a0[ti], a1[ti]);
        __syncthreads();
    }

    const int hP = tid & 255, half = tid >> 8;
    float accv[TI] = {0.f, 0.f};
    if (half == 0) {
#pragma unroll
        for (int ti = 0; ti < TI; ++ti)
            accv[ti] = histS[ti * 256 + hP] + histB[ti * 256 + hP]
                     + hist2S[ti * 256 + hP] + hist2B[ti * 256 + hP];
    }

    // ---- LN1 -> y1 in srow[0..511] ----
    float4 t4;
    float dd[TI];
    t4 = make_float4((half == 0) ? accv[0] : 0.f, (half == 0) ? accv[1] : 0.f, 0.f, 0.f);
    float4 mean4 = blockReduce4(t4, red4b, false);
#pragma unroll
    for (int ti = 0; ti < TI; ++ti) {
        dd[ti] = (half == 0) ? accv[ti] - ((const float*)&mean4)[ti] * (1.f / 256.f) : 0.f;
        ((float*)&t4)[ti] = dd[ti] * dd[ti];
    }
    t4.z = 0.f; t4.w = 0.f;
    float4 var4 = blockReduce4(t4, red4b, false);
    if (half == 0) {
        const float g1v = g1[hP], b1v = b1[hP];
#pragma unroll
        for (int ti = 0; ti < TI; ++ti)
            srow[ti * 256 + hP] = dd[ti] * rsqrtf(((const float*)&var4)[ti] * (1.f / 256.f) + 1e-5f) * g1v + b1v;
    }
    __syncthreads();

    // ---- Wo GEMV: o = tid&255, d-half = tid>>8; Wo^T packed bf16 pairs along d ----
    float acc2[TI] = {0.f, 0.f};
    {
        const u32* wp = wop32 + hP;
        const float4* y4p = (const float4*)srow;
        for (int d8 = half * 16; d8 < half * 16 + 16; ++d8) {   // d = 8*d8, 16 iters
            const int d2 = 4 * d8;
            u32 w01 = wp[(size_t)(d2 + 0) * 256];
            u32 w23 = wp[(size_t)(d2 + 1) * 256];
            u32 w45 = wp[(size_t)(d2 + 2) * 256];
            u32 w67 = wp[(size_t)(d2 + 3) * 256];
            float f0 = blo(w01), f1 = bhi(w01), f2 = blo(w23), f3 = bhi(w23);
            float f4 = blo(w45), f5 = bhi(w45), f6 = blo(w67), f7 = bhi(w67);
#pragma unroll
            for (int ti = 0; ti < TI; ++ti) {
                float4 ya = y4p[ti * 64 + 2 * d8];      // y1[ti*256 + 8*d8 .. +3]
                float4 yb = y4p[ti * 64 + 2 * d8 + 1];  // y1[ti*256 + 8*d8+4 .. +7]
                acc2[ti] += ya.x * f0 + ya.y * f1 + ya.z * f2 + ya.w * f3
                          + yb.x * f4 + yb.y * f5 + yb.z * f6 + yb.w * f7;
            }
        }
        if (half == 1) {
#pragma unroll
            for (int ti = 0; ti < TI; ++ti) histS[ti * 256 + hP] = acc2[ti];
        }
        __syncthreads();
        if (half == 0) {
            const float bov = bo[hP];
#pragma unroll
            for (int ti = 0; ti < TI; ++ti) acc2[ti] += histS[ti * 256 + hP] + bov;
        }
    }

    // ---- LN(g_ot, b_ot) + relu ----
    t4 = make_float4((half == 0) ? acc2[0] : 0.f, (half == 0) ? acc2[1] : 0.f, 0.f, 0.f);
    mean4 = blockReduce4(t4, red4b, false);
#pragma unroll
    for (int ti = 0; ti < TI; ++ti) {
        dd[ti] = (half == 0) ? acc2[ti] - ((const float*)&mean4)[ti] * (1.f / 256.f) : 0.f;
        ((float*)&t4)[ti] = dd[ti] * dd[ti];
    }
    t4.z = 0.f; t4.w = 0.f;
    var4 = blockReduce4(t4, red4b, false);
    float z[TI];
    const float gotv = (half == 0) ? g_ot[hP] : 0.f;
    const float botv = (half == 0) ? b_ot[hP] : 0.f;
#pragma unroll
    for (int ti = 0; ti < TI; ++ti)
        z[ti] = fmaxf(dd[ti] * rsqrtf(((const float*)&var4)[ti] * (1.f / 256.f) + 1e-5f) * gotv + botv, 0.f);

    // ---- residual + LN2 + store ----
    float tt[TI];
#pragma unroll
    for (int ti = 0; ti < TI; ++ti)
        tt[ti] = (half == 0) ? z[ti] + x[(size_t)(b * NN + i0 + ti) * ND + hP] : 0.f;
    t4 = make_float4(tt[0], tt[1], 0.f, 0.f);
    mean4 = blockReduce4(t4, red4b, false);
#pragma unroll
    for (int ti = 0; ti < TI; ++ti) {
        dd[ti] = (half == 0) ? tt[ti] - ((const float*)&mean4)[ti] * (1.f / 256.f) : 0.f;
        ((float*)&t4)[ti] = dd[ti] * dd[ti];
    }
    t4.z = 0.f; t4.w = 0.f;
    var4 = blockReduce4(t4, red4b, false);
    if (half == 0) {
        const float g2v = g2[hP], b2v = b2[hP];
#pragma unroll
        for (int ti = 0; ti < TI; ++ti) {
            float o = dd[ti] * rsqrtf(((const float*)&var4)[ti] * (1.f / 256.f) + 1e-5f) * g2v + b2v;
            out[(size_t)(b * NN + i0 + ti) * NH + hP] = o;
        }
    }
}

extern "C" void kernel_launch(void* const* d_in, const int* in_sizes, int n_in,
                              void* d_out, int out_size, void* d_ws, size_t ws_size,
                              hipStream_t stream) {
    const float* x    = (const float*)d_in[0];
    const float* area = (const float*)d_in[1];
    const float* co   = (const float*)d_in[2];
    const float* Wq   = (const float*)d_in[3];
    const float* bq   = (const float*)d_in[4];
    const float* Wk   = (const float*)d_in[5];
    const float* bk   = (const float*)d_in[6];
    const float* Wv   = (const float*)d_in[7];
    const float* bv   = (const float*)d_in[8];
    const float* We1  = (const float*)d_in[9];
    const float* be1  = (const float*)d_in[10];
    const float* We2  = (const float*)d_in[11];
    const float* be2  = (const float*)d_in[12];
    const float* Wo   = (const float*)d_in[13];
    const float* bo   = (const float*)d_in[14];
    const float* g_ot = (const float*)d_in[15];
    const float* b_ot = (const float*)d_in[16];
    const float* g1   = (const float*)d_in[17];
    const float* b1   = (const float*)d_in[18];
    const float* g2   = (const float*)d_in[19];
    const float* b2   = (const float*)d_in[20];

    float* q  = (float*)d_ws;                          // 2 MB
    u16*  kp  = (u16*)(q + (size_t)2048 * 256);        // 1 MB  [b][h>>1][j][h&1]
    u16*  vp  = kp + (size_t)4 * 128 * 512 * 2;        // 1 MB  [row][h]
    u16*  wop = vp + (size_t)2048 * 256;               // 128 KB [d>>1][o][d&1]

    qkv_mfma<<<dim3(32, 49), 256, 0, stream>>>(x, Wq, bq, Wk, bk, Wv, bv, Wo,
                                               q, kp, vp, wop);
    fused_kernel<<<NB * NN / TI, 512, 0, stream>>>(x, area, co, We1, be1, We2, be2,
                                                   (const u32*)wop, bo,
                                                   g_ot, b_ot, g1, b1, g2, b2,
                                                   q, (const u32*)kp, (const u32*)vp,
                                                   (float*)d_out);
}

// Round 11
// 167.074 us; speedup vs baseline: 1.0874x; 1.0874x over previous
//
#include <hip/hip_runtime.h>

typedef unsigned short u16;
typedef unsigned int u32;

#define NB 4
#define NN 512
#define ND 256
#define NH 256
#define TI 4

typedef __attribute__((ext_vector_type(8))) short short8;
typedef __attribute__((ext_vector_type(4))) float f32x4;

__device__ __forceinline__ short bf(float f) {
    u32 t; __builtin_memcpy(&t, &f, 4);
    u32 r = (t + 0x7FFFu + ((t >> 16) & 1u)) >> 16;
    return (short)(u16)r;
}
__device__ __forceinline__ float blo(u32 u) {
    u32 t = u << 16; float f; __builtin_memcpy(&f, &t, 4); return f;
}
__device__ __forceinline__ float bhi(u32 u) {
    u32 t = u & 0xFFFF0000u; float f; __builtin_memcpy(&f, &t, 4); return f;
}

__device__ __forceinline__ float waveReduceSum(float v) {
#pragma unroll
    for (int o = 32; o > 0; o >>= 1) v += __shfl_down(v, o);
    return v;
}

// block-wide reduce of 4 values across 8 waves (512 threads)
__device__ __forceinline__ float4 blockReduce4(float4 v, float4* red4b, bool ismax) {
#pragma unroll
    for (int o = 32; o > 0; o >>= 1) {
        float4 t;
        t.x = __shfl_down(v.x, o); t.y = __shfl_down(v.y, o);
        t.z = __shfl_down(v.z, o); t.w = __shfl_down(v.w, o);
        if (ismax) {
            v.x = fmaxf(v.x, t.x); v.y = fmaxf(v.y, t.y);
            v.z = fmaxf(v.z, t.z); v.w = fmaxf(v.w, t.w);
        } else {
            v.x += t.x; v.y += t.y; v.z += t.z; v.w += t.w;
        }
    }
    int wid = threadIdx.x >> 6;
    __syncthreads();
    if ((threadIdx.x & 63) == 0) red4b[wid] = v;
    __syncthreads();
    float4 r = red4b[0];
#pragma unroll
    for (int w = 1; w < 8; ++w) {
        float4 u = red4b[w];
        if (ismax) {
            r.x = fmaxf(r.x, u.x); r.y = fmaxf(r.y, u.y);
            r.z = fmaxf(r.z, u.z); r.w = fmaxf(r.w, u.w);
        } else {
            r.x += u.x; r.y += u.y; r.z += u.z; r.w += u.w;
        }
    }
    return r;
}

// ---------------- K1: q/k/v projections via bf16 MFMA (inline cvt) + Wo^T ----------------
// grid (32, 49), 256 thr. y<48: MFMA jobs. y==48: Wo transpose -> packed bf16.
// q fp32 [row][h]; k -> kp u16 [b][h>>1][j][h&1]; v -> vp u16 [row][h]; Wo^T -> wop u16 [d>>1][o][d&1].
__global__ __launch_bounds__(256) void qkv_mfma(
    const float* __restrict__ x,
    const float* __restrict__ Wq, const float* __restrict__ bq,
    const float* __restrict__ Wk, const float* __restrict__ bk,
    const float* __restrict__ Wv, const float* __restrict__ bv,
    const float* __restrict__ Wo,
    float* __restrict__ q, u16* __restrict__ kp, u16* __restrict__ vp,
    u16* __restrict__ wop)
{
    const int tid = threadIdx.x;
    if (blockIdx.y == 48) {
        __shared__ float t[32][33];
        const int tx = tid & 31, ty = tid >> 5;
#pragma unroll
        for (int tt2 = 0; tt2 < 2; ++tt2) {
            const int tile = blockIdx.x * 2 + tt2;    // 0..63
            const int bx = tile & 7, by = tile >> 3;
            __syncthreads();
#pragma unroll
            for (int k = 0; k < 4; ++k)
                t[ty + 8 * k][tx] = Wo[(size_t)(by * 32 + ty + 8 * k) * 256 + bx * 32 + tx];
            __syncthreads();
#pragma unroll
            for (int k = 0; k < 4; ++k) {
                const int d = bx * 32 + ty + 8 * k, o = by * 32 + tx;
                wop[(size_t)(d >> 1) * 512 + 2 * o + (d & 1)] = (u16)bf(t[tx][ty + 8 * k]);
            }
        }
        return;
    }

    const int lane = tid & 63, wave = tid >> 6;
    const int r0 = blockIdx.x * 64 + wave * 16;
    const int out0 = blockIdx.y * 16;                  // 0..767
    const int which = blockIdx.y >> 4;
    const float* W   = (which == 0) ? Wq : (which == 1) ? Wk : Wv;
    const float* bia = (which == 0) ? bq : (which == 1) ? bk : bv;

    const int m = lane & 15, koff = (lane >> 4) * 8;
    const float* Ap = x + (size_t)(r0 + m) * 256 + koff;
    const float* Bp = W + (size_t)((out0 & 255) + m) * 256 + koff;

    f32x4 acc = {0.f, 0.f, 0.f, 0.f};
#pragma unroll
    for (int kb = 0; kb < 8; ++kb) {
        float4 a0 = *(const float4*)(Ap + kb * 32);
        float4 a1 = *(const float4*)(Ap + kb * 32 + 4);
        float4 b0 = *(const float4*)(Bp + kb * 32);
        float4 b1 = *(const float4*)(Bp + kb * 32 + 4);
        short8 af, bf8;
        af[0] = bf(a0.x); af[1] = bf(a0.y); af[2] = bf(a0.z); af[3] = bf(a0.w);
        af[4] = bf(a1.x); af[5] = bf(a1.y); af[6] = bf(a1.z); af[7] = bf(a1.w);
        bf8[0] = bf(b0.x); bf8[1] = bf(b0.y); bf8[2] = bf(b0.z); bf8[3] = bf(b0.w);
        bf8[4] = bf(b1.x); bf8[5] = bf(b1.y); bf8[6] = bf(b1.z); bf8[7] = bf(b1.w);
        acc = __builtin_amdgcn_mfma_f32_16x16x32_bf16(af, bf8, acc, 0, 0, 0);
    }

    const int oc = (out0 + m) & 255;          // D col = lane&15
    const float bias = bia[oc];
    const int rbase = r0 + (lane >> 4) * 4;   // D row = (lane>>4)*4 + reg
#pragma unroll
    for (int reg = 0; reg < 4; ++reg) {
        int R = rbase + reg;
        float val = acc[reg] + bias;
        if (which == 0) {
            q[(size_t)R * 256 + oc] = val;
        } else if (which == 1) {
            const int b_ = R >> 9, n = R & 511;
            kp[((size_t)(b_ * 128 + (oc >> 1)) * 512 + n) * 2 + (oc & 1)] = (u16)bf(val);
        } else {
            vp[(size_t)R * 256 + oc] = (u16)bf(val);
        }
    }
}

// ---------------- K2: fused attention, TI=4 rows, 512 threads, histogram gate ----------------
__global__ __launch_bounds__(512) void fused_kernel(
    const float* __restrict__ x, const float* __restrict__ area, const float* __restrict__ co,
    const float* __restrict__ We1, const float* __restrict__ be1,
    const float* __restrict__ We2, const float* __restrict__ be2,
    const u32* __restrict__ wop32, const float* __restrict__ bo,
    const float* __restrict__ g_ot, const float* __restrict__ b_ot,
    const float* __restrict__ g1, const float* __restrict__ b1,
    const float* __restrict__ g2, const float* __restrict__ b2,
    const float* __restrict__ q, const u32* __restrict__ kp32, const u32* __restrict__ vp32,
    float* __restrict__ out)
{
    const int tid = threadIdx.x;
    const int b = blockIdx.x >> 7;
    const int i0 = (blockIdx.x & 127) << 2;
    const int lane = tid & 63, w = tid >> 6;

    __shared__ float histS[1024], histB[1024], hist2S[1024], hist2B[1024];
    __shared__ float srow[2048];
    __shared__ float4 red4b[8];
    __shared__ float sBaseS[4], sBaseB[4], redA[8], redB[8];

    const float be2f = be2[0];

    // ---- gate: zero hist, scatter hinge deltas, reduce always-active bases ----
    histS[tid] = 0.f; histS[tid + 512] = 0.f;
    histB[tid] = 0.f; histB[tid + 512] = 0.f;
    __syncthreads();
    {
        const int s = tid >> 7, h0 = tid & 127;            // set s = w>>1 (wave-uniform)
        const float a = area[b * NN + i0 + s];
        float baS = 0.f, baB = 0.f;
#pragma unroll
        for (int k = 0; k < 2; ++k) {
            const int h = h0 + 128 * k;
            const float w10 = We1[2 * h], w11 = We1[2 * h + 1];
            const float w2v = We2[h], be1v = be1[h];
            const float al = fmaf(a, w10, be1v);
            const float sl = w11 * w2v, bb = al * w2v;
            if (w11 == 0.f) {
                if (al > 0.f) baB += bb;
            } else {
                float tt = -al / w11;
                if (w11 > 0.f) {
                    if (tt <= 0.f)      { baS += sl; baB += bb; }
                    else if (tt < 1.f) {
                        int u = (int)(tt * 256.f); u = u > 255 ? 255 : u;
                        atomicAdd(&histS[s * 256 + u], sl);
                        atomicAdd(&histB[s * 256 + u], bb);
                    }
                } else {
                    if (tt >= 1.f)      { baS += sl; baB += bb; }
                    else if (tt > 0.f) {
                        baS += sl; baB += bb;
                        int u = (int)(tt * 256.f); u = u > 255 ? 255 : u;
                        atomicAdd(&histS[s * 256 + u], -sl);
                        atomicAdd(&histB[s * 256 + u], -bb);
                    }
                }
            }
        }
        float rS = waveReduceSum(baS), rB = waveReduceSum(baB);
        if (lane == 0) { redA[w] = rS; redB[w] = rB; }
    }
    __syncthreads();
    if (tid < 4) {
        sBaseS[tid] = redA[2 * tid] + redA[2 * tid + 1];
        sBaseB[tid] = redB[2 * tid] + redB[2 * tid + 1];
    }

    // ---- in-place inclusive scan: wave s scans histS set s; wave s+4 scans histB set s.
    //      4 buckets/lane serial + 6-step wave shfl scan; 1 barrier total. ----
    {
        const int s = w & 3;
        float* hp = (w < 4) ? histS : histB;
        float b0 = hp[s * 256 + 4 * lane + 0];
        float b1 = hp[s * 256 + 4 * lane + 1];
        float b2 = hp[s * 256 + 4 * lane + 2];
        float b3 = hp[s * 256 + 4 * lane + 3];
        float p0 = b0, p1 = p0 + b1, p2 = p1 + b2, p3 = p2 + b3;
        float incl = p3;
#pragma unroll
        for (int off = 1; off < 64; off <<= 1) {
            float t = __shfl_up(incl, off);
            if (lane >= off) incl += t;
        }
        float excl = incl - p3;
        hp[s * 256 + 4 * lane + 0] = p0 + excl;
        hp[s * 256 + 4 * lane + 1] = p1 + excl;
        hp[s * 256 + 4 * lane + 2] = p2 + excl;
        hp[s * 256 + 4 * lane + 3] = p3 + excl;
    }
    __syncthreads();

    // ---- QK dot (j = tid) + gate + score; k as packed bf16 pairs along h ----
    float sA[TI];
    {
        const u32* kt = kp32 + (size_t)b * 128 * 512 + tid;
        const float* qb_ = q + (size_t)(b * NN + i0) * NH;
        float dot[TI] = {0.f, 0.f, 0.f, 0.f};
        for (int h = 0; h < 256; h += 4) {   // 64 iters, 2 u32 loads each
            const int h2 = h >> 1;
            u32 ka = kt[(size_t)h2 * 512];
            u32 kb = kt[(size_t)(h2 + 1) * 512];
            float k0 = blo(ka), k1 = bhi(ka), k2 = blo(kb), k3 = bhi(kb);
#pragma unroll
            for (int ti = 0; ti < TI; ++ti) {
                float4 qv = *(const float4*)&qb_[ti * 256 + h];  // wave-uniform -> s_load
                dot[ti] += qv.x * k0 + qv.y * k1 + qv.z * k2 + qv.w * k3;
            }
        }
#pragma unroll
        for (int ti = 0; ti < TI; ++ti) {
            float c = co[(size_t)(i0 + ti) * NN + tid];
            int u = (int)(c * 256.f); u = u > 255 ? 255 : u;
            float S = sBaseS[ti] + histS[ti * 256 + u];
            float B = sBaseB[ti] + histB[ti * 256 + u];
            float e = fmaf(c, S, B) + be2f;
            float ew = 1.f / (1.f + __expf(-e));
            sA[ti] = dot[ti] * 0.0625f * ew;
        }
    }

    // ---- softmax numerator only: LN1 is scale-invariant, so skip the 1/sum normalize ----
    {
        float4 m4 = make_float4(sA[0], sA[1], sA[2], sA[3]);
        m4 = blockReduce4(m4, red4b, true);
#pragma unroll
        for (int ti = 0; ti < TI; ++ti)
            srow[ti * 512 + tid] = __expf(sA[ti] - ((const float*)&m4)[ti]);
        __syncthreads();
    }

    // ---- PV: thread = (h-pair h2, j-quarter qtr); v packed bf16 pairs along h ----
    {
        const int h2 = tid & 127, qtr = tid >> 7;
        float a0[TI] = {0.f, 0.f, 0.f, 0.f};   // h = 2*h2
        float a1[TI] = {0.f, 0.f, 0.f, 0.f};   // h = 2*h2+1
        const u32* vp_ = vp32 + (size_t)b * 512 * 128 + h2;
        const float4* s4p = (const float4*)srow;
        for (int j4 = qtr * 32; j4 < qtr * 32 + 32; ++j4) {
            const int jj = 4 * j4;
            u32 va = vp_[(size_t)(jj + 0) * 128];
            u32 vb = vp_[(size_t)(jj + 1) * 128];
            u32 vc = vp_[(size_t)(jj + 2) * 128];
            u32 vd = vp_[(size_t)(jj + 3) * 128];
            float la = blo(va), ha = bhi(va), lb = blo(vb), hb = bhi(vb);
            float lc = blo(vc), hc = bhi(vc), ld = blo(vd), hd = bhi(vd);
#pragma unroll
            for (int ti = 0; ti < TI; ++ti) {
                float4 p4 = s4p[ti * 128 + j4];  // wave-uniform LDS broadcast
                a0[ti] += p4.x * la + p4.y * lb + p4.z * lc + p4.w * ld;
                a1[ti] += p4.x * ha + p4.y * hb + p4.z * hc + p4.w * hd;
            }
        }
        float2* bq_ = (float2*)((qtr == 0) ? histS : (qtr == 1) ? histB : (qtr == 2) ? hist2S : hist2B);
#pragma unroll
        for (int ti = 0; ti < TI; ++ti) bq_[ti * 128 + h2] = make_float2(a0[ti], a1[ti]);
        __syncthreads();
    }

    const int hP = tid & 255, half = tid >> 8;
    float accv[TI] = {0.f, 0.f, 0.f, 0.f};
    if (half == 0) {
#pragma unroll
        for (int ti = 0; ti < TI; ++ti)
            accv[ti] = histS[ti * 256 + hP] + histB[ti * 256 + hP]
                     + hist2S[ti * 256 + hP] + hist2B[ti * 256 + hP];
    }

    // ---- LN1 -> y1 in srow[0..1023] ----
    float4 t4;
    float dd[TI];
#pragma unroll
    for (int ti = 0; ti < TI; ++ti) ((float*)&t4)[ti] = (half == 0) ? accv[ti] : 0.f;
    float4 mean4 = blockReduce4(t4, red4b, false);
#pragma unroll
    for (int ti = 0; ti < TI; ++ti) {
        dd[ti] = (half == 0) ? accv[ti] - ((const float*)&mean4)[ti] * (1.f / 256.f) : 0.f;
        ((float*)&t4)[ti] = dd[ti] * dd[ti];
    }
    float4 var4 = blockReduce4(t4, red4b, false);
    if (half == 0) {
        const float g1v = g1[hP], b1v = b1[hP];
#pragma unroll
        for (int ti = 0; ti < TI; ++ti)
            srow[ti * 256 + hP] = dd[ti] * rsqrtf(((const float*)&var4)[ti] * (1.f / 256.f) + 1e-5f) * g1v + b1v;
    }
    __syncthreads();

    // ---- Wo GEMV: o = tid&255, d-half = tid>>8; Wo^T packed bf16 pairs along d ----
    float acc2[TI] = {0.f, 0.f, 0.f, 0.f};
    {
        const u32* wp = wop32 + hP;
        const float4* y4p = (const float4*)srow;
        for (int d8 = half * 16; d8 < half * 16 + 16; ++d8) {   // d = 8*d8, 16 iters
            const int d2 = 4 * d8;
            u32 w01 = wp[(size_t)(d2 + 0) * 256];
            u32 w23 = wp[(size_t)(d2 + 1) * 256];
            u32 w45 = wp[(size_t)(d2 + 2) * 256];
            u32 w67 = wp[(size_t)(d2 + 3) * 256];
            float f0 = blo(w01), f1 = bhi(w01), f2 = blo(w23), f3 = bhi(w23);
            float f4 = blo(w45), f5 = bhi(w45), f6 = blo(w67), f7 = bhi(w67);
#pragma unroll
            for (int ti = 0; ti < TI; ++ti) {
                float4 ya = y4p[ti * 64 + 2 * d8];      // y1[ti*256 + 8*d8 .. +3]
                float4 yb = y4p[ti * 64 + 2 * d8 + 1];  // y1[ti*256 + 8*d8+4 .. +7]
                acc2[ti] += ya.x * f0 + ya.y * f1 + ya.z * f2 + ya.w * f3
                          + yb.x * f4 + yb.y * f5 + yb.z * f6 + yb.w * f7;
            }
        }
        if (half == 1) {
#pragma unroll
            for (int ti = 0; ti < TI; ++ti) histS[ti * 256 + hP] = acc2[ti];
        }
        __syncthreads();
        if (half == 0) {
            const float bov = bo[hP];
#pragma unroll
            for (int ti = 0; ti < TI; ++ti) acc2[ti] += histS[ti * 256 + hP] + bov;
        }
    }

    // ---- LN(g_ot, b_ot) + relu ----
#pragma unroll
    for (int ti = 0; ti < TI; ++ti) ((float*)&t4)[ti] = (half == 0) ? acc2[ti] : 0.f;
    mean4 = blockReduce4(t4, red4b, false);
#pragma unroll
    for (int ti = 0; ti < TI; ++ti) {
        dd[ti] = (half == 0) ? acc2[ti] - ((const float*)&mean4)[ti] * (1.f / 256.f) : 0.f;
        ((float*)&t4)[ti] = dd[ti] * dd[ti];
    }
    var4 = blockReduce4(t4, red4b, false);
    float z[TI];
    const float gotv = (half == 0) ? g_ot[hP] : 0.f;
    const float botv = (half == 0) ? b_ot[hP] : 0.f;
#pragma unroll
    for (int ti = 0; ti < TI; ++ti)
        z[ti] = fmaxf(dd[ti] * rsqrtf(((const float*)&var4)[ti] * (1.f / 256.f) + 1e-5f) * gotv + botv, 0.f);

    // ---- residual + LN2 + store ----
    float tt[TI];
#pragma unroll
    for (int ti = 0; ti < TI; ++ti) {
        tt[ti] = (half == 0) ? z[ti] + x[(size_t)(b * NN + i0 + ti) * ND + hP] : 0.f;
        ((float*)&t4)[ti] = tt[ti];
    }
    mean4 = blockReduce4(t4, red4b, false);
#pragma unroll
    for (int ti = 0; ti < TI; ++ti) {
        dd[ti] = (half == 0) ? tt[ti] - ((const float*)&mean4)[ti] * (1.f / 256.f) : 0.f;
        ((float*)&t4)[ti] = dd[ti] * dd[ti];
    }
    var4 = blockReduce4(t4, red4b, false);
    if (half == 0) {
        const float g2v = g2[hP], b2v = b2[hP];
#pragma unroll
        for (int ti = 0; ti < TI; ++ti) {
            float o = dd[ti] * rsqrtf(((const float*)&var4)[ti] * (1.f / 256.f) + 1e-5f) * g2v + b2v;
            out[(size_t)(b * NN + i0 + ti) * NH + hP] = o;
        }
    }
}

extern "C" void kernel_launch(void* const* d_in, const int* in_sizes, int n_in,
                              void* d_out, int out_size, void* d_ws, size_t ws_size,
                              hipStream_t stream) {
    const float* x    = (const float*)d_in[0];
    const float* area = (const float*)d_in[1];
    const float* co   = (const float*)d_in[2];
    const float* Wq   = (const float*)d_in[3];
    const float* bq   = (const float*)d_in[4];
    const float* Wk   = (const float*)d_in[5];
    const float* bk   = (const float*)d_in[6];
    const float* Wv   = (const float*)d_in[7];
    const float* bv   = (const float*)d_in[8];
    const float* We1  = (const float*)d_in[9];
    const float* be1  = (const float*)d_in[10];
    const float* We2  = (const float*)d_in[11];
    const float* be2  = (const float*)d_in[12];
    const float* Wo   = (const float*)d_in[13];
    const float* bo   = (const float*)d_in[14];
    const float* g_ot = (const float*)d_in[15];
    const float* b_ot = (const float*)d_in[16];
    const float* g1   = (const float*)d_in[17];
    const float* b1   = (const float*)d_in[18];
    const float* g2   = (const float*)d_in[19];
    const float* b2   = (const float*)d_in[20];

    float* q  = (float*)d_ws;                          // 2 MB
    u16*  kp  = (u16*)(q + (size_t)2048 * 256);        // 1 MB  [b][h>>1][j][h&1]
    u16*  vp  = kp + (size_t)4 * 128 * 512 * 2;        // 1 MB  [row][h]
    u16*  wop = vp + (size_t)2048 * 256;               // 128 KB [d>>1][o][d&1]

    qkv_mfma<<<dim3(32, 49), 256, 0, stream>>>(x, Wq, bq, Wk, bk, Wv, bv, Wo,
                                               q, kp, vp, wop);
    fused_kernel<<<NB * NN / TI, 512, 0, stream>>>(x, area, co, We1, be1, We2, be2,
                                                   (const u32*)wop, bo,
                                                   g_ot, b_ot, g1, b1, g2, b2,
                                                   q, (const u32*)kp, (const u32*)vp,
                                                   (float*)d_out);
}

// Round 12
// 158.646 us; speedup vs baseline: 1.1452x; 1.0531x over previous
//
#include <hip/hip_runtime.h>

typedef unsigned short u16;
typedef unsigned int u32;

#define NB 4
#define NN 512
#define ND 256
#define NH 256
#define TI 4

typedef __attribute__((ext_vector_type(8))) short short8;
typedef __attribute__((ext_vector_type(4))) float f32x4;

__device__ __forceinline__ short bf(float f) {
    u32 t; __builtin_memcpy(&t, &f, 4);
    u32 r = (t + 0x7FFFu + ((t >> 16) & 1u)) >> 16;
    return (short)(u16)r;
}
__device__ __forceinline__ float blo(u32 u) {
    u32 t = u << 16; float f; __builtin_memcpy(&f, &t, 4); return f;
}
__device__ __forceinline__ float bhi(u32 u) {
    u32 t = u & 0xFFFF0000u; float f; __builtin_memcpy(&f, &t, 4); return f;
}

__device__ __forceinline__ float waveReduceSum(float v) {
#pragma unroll
    for (int o = 32; o > 0; o >>= 1) v += __shfl_down(v, o);
    return v;
}

// block-wide sum-reduce of TWO float4s (8 values) across 8 waves; 2 barriers total.
__device__ __forceinline__ void blockReduce8(float4& va, float4& vb, float4* red) {
#pragma unroll
    for (int o = 32; o > 0; o >>= 1) {
        va.x += __shfl_down(va.x, o); va.y += __shfl_down(va.y, o);
        va.z += __shfl_down(va.z, o); va.w += __shfl_down(va.w, o);
        vb.x += __shfl_down(vb.x, o); vb.y += __shfl_down(vb.y, o);
        vb.z += __shfl_down(vb.z, o); vb.w += __shfl_down(vb.w, o);
    }
    int wid = threadIdx.x >> 6;
    __syncthreads();
    if ((threadIdx.x & 63) == 0) { red[2 * wid] = va; red[2 * wid + 1] = vb; }
    __syncthreads();
    float4 ra = red[0], rb = red[1];
#pragma unroll
    for (int w = 1; w < 8; ++w) {
        float4 ua = red[2 * w], ub = red[2 * w + 1];
        ra.x += ua.x; ra.y += ua.y; ra.z += ua.z; ra.w += ua.w;
        rb.x += ub.x; rb.y += ub.y; rb.z += ub.z; rb.w += ub.w;
    }
    va = ra; vb = rb;
}

// ---------------- K1: q/k/v projections via bf16 MFMA (inline cvt) + Wo^T ----------------
// grid (32, 49), 256 thr. y<48: MFMA jobs -> qb/kb/vp bf16 [row][h].
// y==48: Wo transpose -> wop u16 [d>>3][o][d&7] (8 d-values packed per o).
__global__ __launch_bounds__(256) void qkv_mfma(
    const float* __restrict__ x,
    const float* __restrict__ Wq, const float* __restrict__ bq,
    const float* __restrict__ Wk, const float* __restrict__ bk,
    const float* __restrict__ Wv, const float* __restrict__ bv,
    const float* __restrict__ Wo,
    u16* __restrict__ qb, u16* __restrict__ kb, u16* __restrict__ vp,
    u16* __restrict__ wop)
{
    const int tid = threadIdx.x;
    if (blockIdx.y == 48) {
        __shared__ float t[32][33];
        const int tx = tid & 31, ty = tid >> 5;
#pragma unroll
        for (int tt2 = 0; tt2 < 2; ++tt2) {
            const int tile = blockIdx.x * 2 + tt2;    // 0..63
            const int bx = tile & 7, by = tile >> 3;
            __syncthreads();
#pragma unroll
            for (int k = 0; k < 4; ++k)
                t[ty + 8 * k][tx] = Wo[(size_t)(by * 32 + ty + 8 * k) * 256 + bx * 32 + tx];
            __syncthreads();
#pragma unroll
            for (int k = 0; k < 4; ++k) {
                const int d = bx * 32 + ty + 8 * k, o = by * 32 + tx;
                wop[(size_t)(d >> 3) * 2048 + o * 8 + (d & 7)] = (u16)bf(t[tx][ty + 8 * k]);
            }
        }
        return;
    }

    const int lane = tid & 63, wave = tid >> 6;
    const int r0 = blockIdx.x * 64 + wave * 16;
    const int out0 = blockIdx.y * 16;                  // 0..767
    const int which = blockIdx.y >> 4;
    const float* W   = (which == 0) ? Wq : (which == 1) ? Wk : Wv;
    const float* bia = (which == 0) ? bq : (which == 1) ? bk : bv;
    u16* dst         = (which == 0) ? qb : (which == 1) ? kb : vp;

    const int m = lane & 15, koff = (lane >> 4) * 8;
    const float* Ap = x + (size_t)(r0 + m) * 256 + koff;
    const float* Bp = W + (size_t)((out0 & 255) + m) * 256 + koff;

    f32x4 acc = {0.f, 0.f, 0.f, 0.f};
#pragma unroll
    for (int kb8 = 0; kb8 < 8; ++kb8) {
        float4 a0 = *(const float4*)(Ap + kb8 * 32);
        float4 a1 = *(const float4*)(Ap + kb8 * 32 + 4);
        float4 b0 = *(const float4*)(Bp + kb8 * 32);
        float4 b1 = *(const float4*)(Bp + kb8 * 32 + 4);
        short8 af, bf8;
        af[0] = bf(a0.x); af[1] = bf(a0.y); af[2] = bf(a0.z); af[3] = bf(a0.w);
        af[4] = bf(a1.x); af[5] = bf(a1.y); af[6] = bf(a1.z); af[7] = bf(a1.w);
        bf8[0] = bf(b0.x); bf8[1] = bf(b0.y); bf8[2] = bf(b0.z); bf8[3] = bf(b0.w);
        bf8[4] = bf(b1.x); bf8[5] = bf(b1.y); bf8[6] = bf(b1.z); bf8[7] = bf(b1.w);
        acc = __builtin_amdgcn_mfma_f32_16x16x32_bf16(af, bf8, acc, 0, 0, 0);
    }

    const int oc = (out0 + m) & 255;          // D col = lane&15
    const float bias = bia[oc];
    const int rbase = r0 + (lane >> 4) * 4;   // D row = (lane>>4)*4 + reg
#pragma unroll
    for (int reg = 0; reg < 4; ++reg) {
        int R = rbase + reg;
        dst[(size_t)R * 256 + oc] = (u16)bf(acc[reg] + bias);
    }
}

// ---------------- K1b: S = Q . K^T via bf16 MFMA; wave per 16x16 tile ----------------
// grid (1024), 256 thr. S fp32 [b*512+i][j] (raw dots; fused applies 1/16 and gate).
__global__ __launch_bounds__(256) void s_gemm(
    const u16* __restrict__ qb, const u16* __restrict__ kb, float* __restrict__ S)
{
    const int lane = threadIdx.x & 63, wave = threadIdx.x >> 6;
    const int job = blockIdx.x * 4 + wave;         // 0..4095
    const int b = job >> 10, rem = job & 1023;
    const int i0 = (rem >> 5) * 16, j0 = (rem & 31) * 16;
    const int m = lane & 15, koff = (lane >> 4) * 8;
    const u16* Ap = qb + (size_t)(b * 512 + i0 + m) * 256 + koff;
    const u16* Bp = kb + (size_t)(b * 512 + j0 + m) * 256 + koff;

    f32x4 acc = {0.f, 0.f, 0.f, 0.f};
#pragma unroll
    for (int kb8 = 0; kb8 < 8; ++kb8) {
        short8 a  = *(const short8*)(Ap + kb8 * 32);
        short8 bf8 = *(const short8*)(Bp + kb8 * 32);
        acc = __builtin_amdgcn_mfma_f32_16x16x32_bf16(a, bf8, acc, 0, 0, 0);
    }
    const int col = j0 + m;                    // D col = lane&15 -> j
    const int rbase = i0 + (lane >> 4) * 4;    // D row -> i
#pragma unroll
    for (int reg = 0; reg < 4; ++reg)
        S[(size_t)(b * 512 + rbase + reg) * 512 + col] = acc[reg];
}

// ---------------- K2: fused attention, TI=4 rows, 512 threads ----------------
__global__ __launch_bounds__(512) void fused_kernel(
    const float* __restrict__ x, const float* __restrict__ area, const float* __restrict__ co,
    const float* __restrict__ We1, const float* __restrict__ be1,
    const float* __restrict__ We2, const float* __restrict__ be2,
    const u32* __restrict__ wop32, const float* __restrict__ bo,
    const float* __restrict__ g_ot, const float* __restrict__ b_ot,
    const float* __restrict__ g1, const float* __restrict__ b1,
    const float* __restrict__ g2, const float* __restrict__ b2,
    const float* __restrict__ S, const u32* __restrict__ vp32,
    float* __restrict__ out)
{
    const int tid = threadIdx.x;
    const int b = blockIdx.x >> 7;
    const int i0 = (blockIdx.x & 127) << 2;
    const int lane = tid & 63, w = tid >> 6;

    __shared__ float histS[1024], histB[1024], hist2S[1024], hist2B[1024];
    __shared__ float srow[2048];
    __shared__ float4 red8b[16];
    __shared__ float sBaseS[4], sBaseB[4], redA[8], redB[8];

    const float be2f = be2[0];

    // ---- gate: zero hist, scatter hinge deltas, reduce always-active bases ----
    histS[tid] = 0.f; histS[tid + 512] = 0.f;
    histB[tid] = 0.f; histB[tid + 512] = 0.f;
    __syncthreads();
    {
        const int s = tid >> 7, h0 = tid & 127;            // set s = w>>1 (wave-uniform)
        const float a = area[b * NN + i0 + s];
        float baS = 0.f, baB = 0.f;
#pragma unroll
        for (int k = 0; k < 2; ++k) {
            const int h = h0 + 128 * k;
            const float w10 = We1[2 * h], w11 = We1[2 * h + 1];
            const float w2v = We2[h], be1v = be1[h];
            const float al = fmaf(a, w10, be1v);
            const float sl = w11 * w2v, bb = al * w2v;
            if (w11 == 0.f) {
                if (al > 0.f) baB += bb;
            } else {
                float tt = -al / w11;
                if (w11 > 0.f) {
                    if (tt <= 0.f)      { baS += sl; baB += bb; }
                    else if (tt < 1.f) {
                        int u = (int)(tt * 256.f); u = u > 255 ? 255 : u;
                        atomicAdd(&histS[s * 256 + u], sl);
                        atomicAdd(&histB[s * 256 + u], bb);
                    }
                } else {
                    if (tt >= 1.f)      { baS += sl; baB += bb; }
                    else if (tt > 0.f) {
                        baS += sl; baB += bb;
                        int u = (int)(tt * 256.f); u = u > 255 ? 255 : u;
                        atomicAdd(&histS[s * 256 + u], -sl);
                        atomicAdd(&histB[s * 256 + u], -bb);
                    }
                }
            }
        }
        float rS = waveReduceSum(baS), rB = waveReduceSum(baB);
        if (lane == 0) { redA[w] = rS; redB[w] = rB; }
    }
    __syncthreads();
    if (tid < 4) {
        sBaseS[tid] = redA[2 * tid] + redA[2 * tid + 1];
        sBaseB[tid] = redB[2 * tid] + redB[2 * tid + 1];
    }

    // ---- in-place inclusive scan: wave s scans histS set s; wave s+4 scans histB set s ----
    {
        const int s = w & 3;
        float* hp = (w < 4) ? histS : histB;
        float b0 = hp[s * 256 + 4 * lane + 0];
        float b1 = hp[s * 256 + 4 * lane + 1];
        float b2 = hp[s * 256 + 4 * lane + 2];
        float b3 = hp[s * 256 + 4 * lane + 3];
        float p0 = b0, p1 = p0 + b1, p2 = p1 + b2, p3 = p2 + b3;
        float incl = p3;
#pragma unroll
        for (int off = 1; off < 64; off <<= 1) {
            float t = __shfl_up(incl, off);
            if (lane >= off) incl += t;
        }
        float excl = incl - p3;
        hp[s * 256 + 4 * lane + 0] = p0 + excl;
        hp[s * 256 + 4 * lane + 1] = p1 + excl;
        hp[s * 256 + 4 * lane + 2] = p2 + excl;
        hp[s * 256 + 4 * lane + 3] = p3 + excl;
    }
    __syncthreads();

    // ---- scores: dot from precomputed S (coalesced), gate, unnormalized exp ----
    {
        const float* Sp = S + (size_t)(b * NN + i0) * 512 + tid;
#pragma unroll
        for (int ti = 0; ti < TI; ++ti) {
            float c = co[(size_t)(i0 + ti) * NN + tid];
            int u = (int)(c * 256.f); u = u > 255 ? 255 : u;
            float Sg = sBaseS[ti] + histS[ti * 256 + u];
            float Bg = sBaseB[ti] + histB[ti * 256 + u];
            float e = fmaf(c, Sg, Bg) + be2f;
            float ew = 1.f / (1.f + __expf(-e));
            // LN1 is invariant to positive per-row scales: skip max-sub and 1/sum.
            srow[ti * 512 + tid] = __expf(Sp[(size_t)ti * 512] * 0.0625f * ew);
        }
        __syncthreads();
    }

    // ---- PV: thread = (h-pair h2, j-quarter qtr); v packed bf16 pairs along h ----
    {
        const int h2 = tid & 127, qtr = tid >> 7;
        float a0[TI] = {0.f, 0.f, 0.f, 0.f};   // h = 2*h2
        float a1[TI] = {0.f, 0.f, 0.f, 0.f};   // h = 2*h2+1
        const u32* vp_ = vp32 + (size_t)b * 512 * 128 + h2;
        const float4* s4p = (const float4*)srow;
        for (int j4 = qtr * 32; j4 < qtr * 32 + 32; ++j4) {
            const int jj = 4 * j4;
            u32 va = vp_[(size_t)(jj + 0) * 128];
            u32 vb = vp_[(size_t)(jj + 1) * 128];
            u32 vc = vp_[(size_t)(jj + 2) * 128];
            u32 vd = vp_[(size_t)(jj + 3) * 128];
            float la = blo(va), ha = bhi(va), lb = blo(vb), hb = bhi(vb);
            float lc = blo(vc), hc = bhi(vc), ld = blo(vd), hd = bhi(vd);
#pragma unroll
            for (int ti = 0; ti < TI; ++ti) {
                float4 p4 = s4p[ti * 128 + j4];  // wave-uniform LDS broadcast
                a0[ti] += p4.x * la + p4.y * lb + p4.z * lc + p4.w * ld;
                a1[ti] += p4.x * ha + p4.y * hb + p4.z * hc + p4.w * hd;
            }
        }
        float2* bq_ = (float2*)((qtr == 0) ? histS : (qtr == 1) ? histB : (qtr == 2) ? hist2S : hist2B);
#pragma unroll
        for (int ti = 0; ti < TI; ++ti) bq_[ti * 128 + h2] = make_float2(a0[ti], a1[ti]);
        __syncthreads();
    }

    const int hP = tid & 255, half = tid >> 8;
    float accv[TI] = {0.f, 0.f, 0.f, 0.f};
    if (half == 0) {
#pragma unroll
        for (int ti = 0; ti < TI; ++ti)
            accv[ti] = histS[ti * 256 + hP] + histB[ti * 256 + hP]
                     + hist2S[ti * 256 + hP] + hist2B[ti * 256 + hP];
    }

    // ---- LN1 -> y1 in srow[0..1023] (single-pass mean/var) ----
    float4 sa, sb;
    float dd[TI];
#pragma unroll
    for (int ti = 0; ti < TI; ++ti) {
        float v = (half == 0) ? accv[ti] : 0.f;
        ((float*)&sa)[ti] = v; ((float*)&sb)[ti] = v * v;
    }
    blockReduce8(sa, sb, red8b);
    if (half == 0) {
        const float g1v = g1[hP], b1v = b1[hP];
#pragma unroll
        for (int ti = 0; ti < TI; ++ti) {
            float mean = ((const float*)&sa)[ti] * (1.f / 256.f);
            float var = fmaxf(((const float*)&sb)[ti] * (1.f / 256.f) - mean * mean, 0.f);
            srow[ti * 256 + hP] = (accv[ti] - mean) * rsqrtf(var + 1e-5f) * g1v + b1v;
        }
    }
    __syncthreads();

    // ---- Wo GEMV: o = tid&255, d-half = tid>>8; Wo^T packed 8-wide -> uint4 loads ----
    float acc2[TI] = {0.f, 0.f, 0.f, 0.f};
    {
        const float4* y4p = (const float4*)srow;
        for (int g = half * 16; g < half * 16 + 16; ++g) {   // d = 8g..8g+7
            uint4 ww = *(const uint4*)(wop32 + (size_t)g * 1024 + hP * 4);
            float f0 = blo(ww.x), f1 = bhi(ww.x), f2 = blo(ww.y), f3 = bhi(ww.y);
            float f4 = blo(ww.z), f5 = bhi(ww.z), f6 = blo(ww.w), f7 = bhi(ww.w);
#pragma unroll
            for (int ti = 0; ti < TI; ++ti) {
                float4 ya = y4p[ti * 64 + 2 * g];
                float4 yb = y4p[ti * 64 + 2 * g + 1];
                acc2[ti] += ya.x * f0 + ya.y * f1 + ya.z * f2 + ya.w * f3
                          + yb.x * f4 + yb.y * f5 + yb.z * f6 + yb.w * f7;
            }
        }
        if (half == 1) {
#pragma unroll
            for (int ti = 0; ti < TI; ++ti) histS[ti * 256 + hP] = acc2[ti];
        }
        __syncthreads();
        if (half == 0) {
            const float bov = bo[hP];
#pragma unroll
            for (int ti = 0; ti < TI; ++ti) acc2[ti] += histS[ti * 256 + hP] + bov;
        }
    }

    // ---- LN(g_ot, b_ot) + relu (single-pass) ----
#pragma unroll
    for (int ti = 0; ti < TI; ++ti) {
        float v = (half == 0) ? acc2[ti] : 0.f;
        ((float*)&sa)[ti] = v; ((float*)&sb)[ti] = v * v;
    }
    blockReduce8(sa, sb, red8b);
    float z[TI];
    const float gotv = (half == 0) ? g_ot[hP] : 0.f;
    const float botv = (half == 0) ? b_ot[hP] : 0.f;
#pragma unroll
    for (int ti = 0; ti < TI; ++ti) {
        float mean = ((const float*)&sa)[ti] * (1.f / 256.f);
        float var = fmaxf(((const float*)&sb)[ti] * (1.f / 256.f) - mean * mean, 0.f);
        dd[ti] = (half == 0) ? acc2[ti] - mean : 0.f;
        z[ti] = fmaxf(dd[ti] * rsqrtf(var + 1e-5f) * gotv + botv, 0.f);
    }

    // ---- residual + LN2 + store (single-pass) ----
    float tt[TI];
#pragma unroll
    for (int ti = 0; ti < TI; ++ti) {
        tt[ti] = (half == 0) ? z[ti] + x[(size_t)(b * NN + i0 + ti) * ND + hP] : 0.f;
        ((float*)&sa)[ti] = tt[ti]; ((float*)&sb)[ti] = tt[ti] * tt[ti];
    }
    blockReduce8(sa, sb, red8b);
    if (half == 0) {
        const float g2v = g2[hP], b2v = b2[hP];
#pragma unroll
        for (int ti = 0; ti < TI; ++ti) {
            float mean = ((const float*)&sa)[ti] * (1.f / 256.f);
            float var = fmaxf(((const float*)&sb)[ti] * (1.f / 256.f) - mean * mean, 0.f);
            float o = (tt[ti] - mean) * rsqrtf(var + 1e-5f) * g2v + b2v;
            out[(size_t)(b * NN + i0 + ti) * NH + hP] = o;
        }
    }
}

extern "C" void kernel_launch(void* const* d_in, const int* in_sizes, int n_in,
                              void* d_out, int out_size, void* d_ws, size_t ws_size,
                              hipStream_t stream) {
    const float* x    = (const float*)d_in[0];
    const float* area = (const float*)d_in[1];
    const float* co   = (const float*)d_in[2];
    const float* Wq   = (const float*)d_in[3];
    const float* bq   = (const float*)d_in[4];
    const float* Wk   = (const float*)d_in[5];
    const float* bk   = (const float*)d_in[6];
    const float* Wv   = (const float*)d_in[7];
    const float* bv   = (const float*)d_in[8];
    const float* We1  = (const float*)d_in[9];
    const float* be1  = (const float*)d_in[10];
    const float* We2  = (const float*)d_in[11];
    const float* be2  = (const float*)d_in[12];
    const float* Wo   = (const float*)d_in[13];
    const float* bo   = (const float*)d_in[14];
    const float* g_ot = (const float*)d_in[15];
    const float* b_ot = (const float*)d_in[16];
    const float* g1   = (const float*)d_in[17];
    const float* b1   = (const float*)d_in[18];
    const float* g2   = (const float*)d_in[19];
    const float* b2   = (const float*)d_in[20];

    u16*  qb  = (u16*)d_ws;                      // 1 MB  bf16 [row][h]
    u16*  kb  = qb + (size_t)2048 * 256;         // 1 MB  bf16 [row][h]
    u16*  vp  = kb + (size_t)2048 * 256;         // 1 MB  bf16 [row][h]
    u16*  wop = vp + (size_t)2048 * 256;         // 128 KB [d>>3][o][d&7]
    float* S  = (float*)(wop + 65536);           // 4 MB  fp32 [b*512+i][j]

    qkv_mfma<<<dim3(32, 49), 256, 0, stream>>>(x, Wq, bq, Wk, bk, Wv, bv, Wo,
                                               qb, kb, vp, wop);
    s_gemm<<<1024, 256, 0, stream>>>(qb, kb, S);
    fused_kernel<<<NB * NN / TI, 512, 0, stream>>>(x, area, co, We1, be1, We2, be2,
                                                   (const u32*)wop, bo,
                                                   g_ot, b_ot, g1, b1, g2, b2,
                                                   S, (const u32*)vp,
                                                   (float*)d_out);
}

// Round 13
// 155.322 us; speedup vs baseline: 1.1697x; 1.0214x over previous
//
#include <hip/hip_runtime.h>

typedef unsigned short u16;
typedef unsigned int u32;

#define NB 4
#define NN 512
#define ND 256
#define NH 256
#define TI 4

typedef __attribute__((ext_vector_type(8))) short short8;
typedef __attribute__((ext_vector_type(4))) float f32x4;

__device__ __forceinline__ u16 bfq(float f) {
    u32 t; __builtin_memcpy(&t, &f, 4);
    u32 r = (t + 0x7FFFu + ((t >> 16) & 1u)) >> 16;
    return (u16)r;
}

__device__ __forceinline__ float waveReduceSum(float v) {
#pragma unroll
    for (int o = 32; o > 0; o >>= 1) v += __shfl_down(v, o);
    return v;
}

// block-wide sum-reduce of TWO float4s (8 values) across 8 waves; 2 barriers total.
__device__ __forceinline__ void blockReduce8(float4& va, float4& vb, float4* red) {
#pragma unroll
    for (int o = 32; o > 0; o >>= 1) {
        va.x += __shfl_down(va.x, o); va.y += __shfl_down(va.y, o);
        va.z += __shfl_down(va.z, o); va.w += __shfl_down(va.w, o);
        vb.x += __shfl_down(vb.x, o); vb.y += __shfl_down(vb.y, o);
        vb.z += __shfl_down(vb.z, o); vb.w += __shfl_down(vb.w, o);
    }
    int wid = threadIdx.x >> 6;
    __syncthreads();
    if ((threadIdx.x & 63) == 0) { red[2 * wid] = va; red[2 * wid + 1] = vb; }
    __syncthreads();
    float4 ra = red[0], rb = red[1];
#pragma unroll
    for (int w = 1; w < 8; ++w) {
        float4 ua = red[2 * w], ub = red[2 * w + 1];
        ra.x += ua.x; ra.y += ua.y; ra.z += ua.z; ra.w += ua.w;
        rb.x += ub.x; rb.y += ub.y; rb.z += ub.z; rb.w += ub.w;
    }
    va = ra; vb = rb;
}

// ---------------- K0: fp32 -> bf16 convert (x, Wq, Wk, Wv, Wo) ----------------
// wb layout: [which][65536], which 0..3 = Wq, Wk, Wv, Wo (row-major, no transpose).
__global__ __launch_bounds__(256) void prep_kernel(
    const float* __restrict__ x, const float* __restrict__ Wq,
    const float* __restrict__ Wk, const float* __restrict__ Wv,
    const float* __restrict__ Wo,
    u16* __restrict__ xb, u16* __restrict__ wb)
{
    const int idx4 = (blockIdx.x * 256 + threadIdx.x) * 4;   // grid covers 786432
    const float* src;
    u16* dst;
    int off;
    if (idx4 < 524288) { src = x; dst = xb; off = idx4; }
    else {
        int u = idx4 - 524288;
        int which = u >> 16; off = u & 65535;
        src = (which == 0) ? Wq : (which == 1) ? Wk : (which == 2) ? Wv : Wo;
        dst = wb + which * 65536;
    }
    float4 f = *(const float4*)(src + off);
    u32 lo = (u32)bfq(f.x) | ((u32)bfq(f.y) << 16);
    u32 hi = (u32)bfq(f.z) | ((u32)bfq(f.w) << 16);
    *(uint2*)(dst + off) = make_uint2(lo, hi);
}

// ---------------- K1: q/k/v projections, pure bf16 MFMA ----------------
// grid (32, 48). qb, kb bf16 [row][h]; v stored TRANSPOSED vt[b][h][j] bf16.
__global__ __launch_bounds__(256) void qkv_mfma(
    const u16* __restrict__ xb, const u16* __restrict__ wb,
    const float* __restrict__ bq, const float* __restrict__ bk, const float* __restrict__ bv,
    u16* __restrict__ qb, u16* __restrict__ kb, u16* __restrict__ vt)
{
    const int lane = threadIdx.x & 63, wave = threadIdx.x >> 6;
    const int r0 = blockIdx.x * 64 + wave * 16;
    const int out0 = blockIdx.y * 16;                  // 0..767
    const int which = blockIdx.y >> 4;
    const float* bia = (which == 0) ? bq : (which == 1) ? bk : bv;

    const int m = lane & 15, koff = (lane >> 4) * 8;
    const u16* Ap = xb + (size_t)(r0 + m) * 256 + koff;
    const u16* Bp = wb + which * 65536 + (size_t)((out0 & 255) + m) * 256 + koff;

    f32x4 acc = {0.f, 0.f, 0.f, 0.f};
#pragma unroll
    for (int ks = 0; ks < 8; ++ks) {
        short8 a  = *(const short8*)(Ap + ks * 32);
        short8 bb = *(const short8*)(Bp + ks * 32);
        acc = __builtin_amdgcn_mfma_f32_16x16x32_bf16(a, bb, acc, 0, 0, 0);
    }

    const int oc = (out0 + m) & 255;          // D col = lane&15
    const float bias = bia[oc];
    const int rbase = r0 + (lane >> 4) * 4;   // D row = (lane>>4)*4 + reg
#pragma unroll
    for (int reg = 0; reg < 4; ++reg) {
        int R = rbase + reg;
        u16 val = bfq(acc[reg] + bias);
        if (which == 0)      qb[(size_t)R * 256 + oc] = val;
        else if (which == 1) kb[(size_t)R * 256 + oc] = val;
        else                 vt[((size_t)(R >> 9) * 256 + oc) * 512 + (R & 511)] = val;
    }
}

// ---------------- K1b: S = Q . K^T via bf16 MFMA; wave per 16x16 tile ----------------
__global__ __launch_bounds__(256) void s_gemm(
    const u16* __restrict__ qb, const u16* __restrict__ kb, float* __restrict__ S)
{
    const int lane = threadIdx.x & 63, wave = threadIdx.x >> 6;
    const int job = blockIdx.x * 4 + wave;         // 0..4095
    const int b = job >> 10, rem = job & 1023;
    const int i0 = (rem >> 5) * 16, j0 = (rem & 31) * 16;
    const int m = lane & 15, koff = (lane >> 4) * 8;
    const u16* Ap = qb + (size_t)(b * 512 + i0 + m) * 256 + koff;
    const u16* Bp = kb + (size_t)(b * 512 + j0 + m) * 256 + koff;

    f32x4 acc = {0.f, 0.f, 0.f, 0.f};
#pragma unroll
    for (int ks = 0; ks < 8; ++ks) {
        short8 a   = *(const short8*)(Ap + ks * 32);
        short8 bb  = *(const short8*)(Bp + ks * 32);
        acc = __builtin_amdgcn_mfma_f32_16x16x32_bf16(a, bb, acc, 0, 0, 0);
    }
    const int col = j0 + m;
    const int rbase = i0 + (lane >> 4) * 4;
#pragma unroll
    for (int reg = 0; reg < 4; ++reg)
        S[(size_t)(b * 512 + rbase + reg) * 512 + col] = acc[reg];
}

// ---------------- K2: fused attention; PV and Wo on the MFMA pipe ----------------
#define PSTR 520   // srow16 row stride (u16): 512 + 8 pad -> 2-way-free LDS banks
#define YSTR 264   // y16 row stride (u16): 256 + 8 pad
__global__ __launch_bounds__(512) void fused_kernel(
    const float* __restrict__ x, const float* __restrict__ area, const float* __restrict__ co,
    const float* __restrict__ We1, const float* __restrict__ be1,
    const float* __restrict__ We2, const float* __restrict__ be2,
    const u16* __restrict__ wob, const float* __restrict__ bo,
    const float* __restrict__ g_ot, const float* __restrict__ b_ot,
    const float* __restrict__ g1, const float* __restrict__ b1,
    const float* __restrict__ g2, const float* __restrict__ b2,
    const float* __restrict__ S, const u16* __restrict__ vt,
    float* __restrict__ out)
{
    const int tid = threadIdx.x;
    const int b = blockIdx.x >> 7;
    const int i0 = (blockIdx.x & 127) << 2;
    const int lane = tid & 63, w = tid >> 6;

    __shared__ float histS[1024], histB[1024];
    __shared__ float pvbuf[1024];
    __shared__ u16 srow16[16 * PSTR];     // P bf16, rows 4..15 zero
    __shared__ u16 y16[16 * YSTR];        // y1 bf16, rows 4..15 zero
    __shared__ float4 red8b[16];
    __shared__ float sBaseS[4], sBaseB[4], redA[8], redB[8];

    const float be2f = be2[0];

    // ---- init: zero hist + bf16 staging buffers ----
    histS[tid] = 0.f; histS[tid + 512] = 0.f;
    histB[tid] = 0.f; histB[tid + 512] = 0.f;
    {
        u32* s32 = (u32*)srow16;                 // 4160 u32
        for (int i = tid; i < 4160; i += 512) s32[i] = 0u;
        u32* y32 = (u32*)y16;                    // 2112 u32
        for (int i = tid; i < 2112; i += 512) y32[i] = 0u;
    }
    __syncthreads();

    // ---- gate: scatter hinge deltas into histogram, reduce always-active bases ----
    {
        const int s = tid >> 7, h0 = tid & 127;  // set s = w>>1 (wave-uniform)
        const float a = area[b * NN + i0 + s];
        float baS = 0.f, baB = 0.f;
#pragma unroll
        for (int k = 0; k < 2; ++k) {
            const int h = h0 + 128 * k;
            const float w10 = We1[2 * h], w11 = We1[2 * h + 1];
            const float w2v = We2[h], be1v = be1[h];
            const float al = fmaf(a, w10, be1v);
            const float sl = w11 * w2v, bb = al * w2v;
            if (w11 == 0.f) {
                if (al > 0.f) baB += bb;
            } else {
                float tt = -al / w11;
                if (w11 > 0.f) {
                    if (tt <= 0.f)      { baS += sl; baB += bb; }
                    else if (tt < 1.f) {
                        int u = (int)(tt * 256.f); u = u > 255 ? 255 : u;
                        atomicAdd(&histS[s * 256 + u], sl);
                        atomicAdd(&histB[s * 256 + u], bb);
                    }
                } else {
                    if (tt >= 1.f)      { baS += sl; baB += bb; }
                    else if (tt > 0.f) {
                        baS += sl; baB += bb;
                        int u = (int)(tt * 256.f); u = u > 255 ? 255 : u;
                        atomicAdd(&histS[s * 256 + u], -sl);
                        atomicAdd(&histB[s * 256 + u], -bb);
                    }
                }
            }
        }
        float rS = waveReduceSum(baS), rB = waveReduceSum(baB);
        if (lane == 0) { redA[w] = rS; redB[w] = rB; }
    }
    __syncthreads();
    if (tid < 4) {
        sBaseS[tid] = redA[2 * tid] + redA[2 * tid + 1];
        sBaseB[tid] = redB[2 * tid] + redB[2 * tid + 1];
    }

    // ---- in-place inclusive scan: wave s scans histS set s; wave s+4 scans histB set s ----
    {
        const int s = w & 3;
        float* hp = (w < 4) ? histS : histB;
        float b0 = hp[s * 256 + 4 * lane + 0];
        float b1 = hp[s * 256 + 4 * lane + 1];
        float b2 = hp[s * 256 + 4 * lane + 2];
        float b3 = hp[s * 256 + 4 * lane + 3];
        float p0 = b0, p1 = p0 + b1, p2 = p1 + b2, p3 = p2 + b3;
        float incl = p3;
#pragma unroll
        for (int off = 1; off < 64; off <<= 1) {
            float t = __shfl_up(incl, off);
            if (lane >= off) incl += t;
        }
        float excl = incl - p3;
        hp[s * 256 + 4 * lane + 0] = p0 + excl;
        hp[s * 256 + 4 * lane + 1] = p1 + excl;
        hp[s * 256 + 4 * lane + 2] = p2 + excl;
        hp[s * 256 + 4 * lane + 3] = p3 + excl;
    }
    __syncthreads();

    // ---- scores: gate + unnormalized exp -> P bf16 in LDS (rows 0..3) ----
    // LN1 is invariant to positive per-row scales: no max-sub, no 1/sum.
    {
        const float* Sp = S + (size_t)(b * NN + i0) * 512 + tid;
#pragma unroll
        for (int ti = 0; ti < TI; ++ti) {
            float c = co[(size_t)(i0 + ti) * NN + tid];
            int u = (int)(c * 256.f); u = u > 255 ? 255 : u;
            float Sg = sBaseS[ti] + histS[ti * 256 + u];
            float Bg = sBaseB[ti] + histB[ti * 256 + u];
            float e = fmaf(c, Sg, Bg) + be2f;
            float ew = 1.f / (1.f + __expf(-e));
            srow16[ti * PSTR + tid] = bfq(__expf(Sp[(size_t)ti * 512] * 0.0625f * ew));
        }
        __syncthreads();
    }

    // ---- PV via MFMA: D[i][h] = sum_j P[i][j] * vt[h][j]; wave w owns h-tiles 2w, 2w+1 ----
    {
        const int m = lane & 15, koff = (lane >> 4) * 8;
        const int t0 = 2 * w, t1 = 2 * w + 1;
        const u16* B0p = vt + ((size_t)(b * 256 + t0 * 16 + m)) * 512 + koff;
        const u16* B1p = vt + ((size_t)(b * 256 + t1 * 16 + m)) * 512 + koff;
        const u16* Arow = srow16 + m * PSTR + koff;
        f32x4 acc0 = {0.f, 0.f, 0.f, 0.f}, acc1 = {0.f, 0.f, 0.f, 0.f};
#pragma unroll
        for (int ks = 0; ks < 16; ++ks) {
            short8 a  = *(const short8*)(Arow + ks * 32);
            short8 b0 = *(const short8*)(B0p + ks * 32);
            short8 b1 = *(const short8*)(B1p + ks * 32);
            acc0 = __builtin_amdgcn_mfma_f32_16x16x32_bf16(a, b0, acc0, 0, 0, 0);
            acc1 = __builtin_amdgcn_mfma_f32_16x16x32_bf16(a, b1, acc1, 0, 0, 0);
        }
        __syncthreads();                 // all reads of srow16 done; pvbuf free
        if (lane < 16) {                 // rows 0..3 live in lanes 0..15, regs 0..3
#pragma unroll
            for (int reg = 0; reg < 4; ++reg) {
                pvbuf[reg * 256 + t0 * 16 + lane] = acc0[reg];
                pvbuf[reg * 256 + t1 * 16 + lane] = acc1[reg];
            }
        }
        __syncthreads();
    }

    // ---- LN1 (single-pass mean/var) -> y1 bf16 in LDS ----
    const int hP = tid & 255, half = tid >> 8;
    float4 sa, sb;
    float accv[TI];
#pragma unroll
    for (int ti = 0; ti < TI; ++ti) {
        accv[ti] = (half == 0) ? pvbuf[ti * 256 + hP] : 0.f;
        ((float*)&sa)[ti] = accv[ti];
        ((float*)&sb)[ti] = accv[ti] * accv[ti];
    }
    blockReduce8(sa, sb, red8b);
    if (half == 0) {
        const float g1v = g1[hP], b1v = b1[hP];
#pragma unroll
        for (int ti = 0; ti < TI; ++ti) {
            float mean = ((const float*)&sa)[ti] * (1.f / 256.f);
            float var = fmaxf(((const float*)&sb)[ti] * (1.f / 256.f) - mean * mean, 0.f);
            y16[ti * YSTR + hP] = bfq((accv[ti] - mean) * rsqrtf(var + 1e-5f) * g1v + b1v);
        }
    }
    __syncthreads();

    // ---- Wo via MFMA: D[i][o] = sum_d y1[i][d] * Wo[o][d]; wob row-major bf16 ----
    {
        const int m = lane & 15, koff = (lane >> 4) * 8;
        const int t0 = 2 * w, t1 = 2 * w + 1;
        const u16* B0p = wob + (size_t)(t0 * 16 + m) * 256 + koff;
        const u16* B1p = wob + (size_t)(t1 * 16 + m) * 256 + koff;
        const u16* Arow = y16 + m * YSTR + koff;
        f32x4 acc0 = {0.f, 0.f, 0.f, 0.f}, acc1 = {0.f, 0.f, 0.f, 0.f};
#pragma unroll
        for (int ks = 0; ks < 8; ++ks) {
            short8 a  = *(const short8*)(Arow + ks * 32);
            short8 b0 = *(const short8*)(B0p + ks * 32);
            short8 b1 = *(const short8*)(B1p + ks * 32);
            acc0 = __builtin_amdgcn_mfma_f32_16x16x32_bf16(a, b0, acc0, 0, 0, 0);
            acc1 = __builtin_amdgcn_mfma_f32_16x16x32_bf16(a, b1, acc1, 0, 0, 0);
        }
        __syncthreads();                 // pvbuf's previous readers done
        if (lane < 16) {
#pragma unroll
            for (int reg = 0; reg < 4; ++reg) {
                pvbuf[reg * 256 + t0 * 16 + lane] = acc0[reg];
                pvbuf[reg * 256 + t1 * 16 + lane] = acc1[reg];
            }
        }
        __syncthreads();
    }

    // ---- + bo, LN(g_ot,b_ot) + relu (single-pass) ----
    float acc2[TI];
    {
        const float bov = (half == 0) ? bo[hP] : 0.f;
#pragma unroll
        for (int ti = 0; ti < TI; ++ti) {
            acc2[ti] = (half == 0) ? pvbuf[ti * 256 + hP] + bov : 0.f;
            ((float*)&sa)[ti] = acc2[ti];
            ((float*)&sb)[ti] = acc2[ti] * acc2[ti];
        }
    }
    blockReduce8(sa, sb, red8b);
    float z[TI];
    const float gotv = (half == 0) ? g_ot[hP] : 0.f;
    const float botv = (half == 0) ? b_ot[hP] : 0.f;
#pragma unroll
    for (int ti = 0; ti < TI; ++ti) {
        float mean = ((const float*)&sa)[ti] * (1.f / 256.f);
        float var = fmaxf(((const float*)&sb)[ti] * (1.f / 256.f) - mean * mean, 0.f);
        z[ti] = fmaxf((acc2[ti] - mean) * rsqrtf(var + 1e-5f) * gotv + botv, 0.f);
    }

    // ---- residual + LN2 + store (single-pass) ----
    float tt[TI];
#pragma unroll
    for (int ti = 0; ti < TI; ++ti) {
        tt[ti] = (half == 0) ? z[ti] + x[(size_t)(b * NN + i0 + ti) * ND + hP] : 0.f;
        ((float*)&sa)[ti] = tt[ti]; ((float*)&sb)[ti] = tt[ti] * tt[ti];
    }
    blockReduce8(sa, sb, red8b);
    if (half == 0) {
        const float g2v = g2[hP], b2v = b2[hP];
#pragma unroll
        for (int ti = 0; ti < TI; ++ti) {
            float mean = ((const float*)&sa)[ti] * (1.f / 256.f);
            float var = fmaxf(((const float*)&sb)[ti] * (1.f / 256.f) - mean * mean, 0.f);
            float o = (tt[ti] - mean) * rsqrtf(var + 1e-5f) * g2v + b2v;
            out[(size_t)(b * NN + i0 + ti) * NH + hP] = o;
        }
    }
}

extern "C" void kernel_launch(void* const* d_in, const int* in_sizes, int n_in,
                              void* d_out, int out_size, void* d_ws, size_t ws_size,
                              hipStream_t stream) {
    const float* x    = (const float*)d_in[0];
    const float* area = (const float*)d_in[1];
    const float* co   = (const float*)d_in[2];
    const float* Wq   = (const float*)d_in[3];
    const float* bq   = (const float*)d_in[4];
    const float* Wk   = (const float*)d_in[5];
    const float* bk   = (const float*)d_in[6];
    const float* Wv   = (const float*)d_in[7];
    const float* bv   = (const float*)d_in[8];
    const float* We1  = (const float*)d_in[9];
    const float* be1  = (const float*)d_in[10];
    const float* We2  = (const float*)d_in[11];
    const float* be2  = (const float*)d_in[12];
    const float* Wo   = (const float*)d_in[13];
    const float* bo   = (const float*)d_in[14];
    const float* g_ot = (const float*)d_in[15];
    const float* b_ot = (const float*)d_in[16];
    const float* g1   = (const float*)d_in[17];
    const float* b1   = (const float*)d_in[18];
    const float* g2   = (const float*)d_in[19];
    const float* b2   = (const float*)d_in[20];

    u16*  xb  = (u16*)d_ws;                      // 1 MB   bf16 x [row][d]
    u16*  wb  = xb + (size_t)2048 * 256;         // 512 KB bf16 [Wq|Wk|Wv|Wo] row-major
    u16*  qb  = wb + (size_t)4 * 65536;          // 1 MB   bf16 q [row][h]
    u16*  kb  = qb + (size_t)2048 * 256;         // 1 MB   bf16 k [row][h]
    u16*  vt  = kb + (size_t)2048 * 256;         // 1 MB   bf16 v TRANSPOSED [b][h][j]
    float* S  = (float*)(vt + (size_t)2048 * 256);  // 4 MB fp32 scores

    prep_kernel<<<768, 256, 0, stream>>>(x, Wq, Wk, Wv, Wo, xb, wb);
    qkv_mfma<<<dim3(32, 48), 256, 0, stream>>>(xb, wb, bq, bk, bv, qb, kb, vt);
    s_gemm<<<1024, 256, 0, stream>>>(qb, kb, S);
    fused_kernel<<<NB * NN / TI, 512, 0, stream>>>(x, area, co, We1, be1, We2, be2,
                                                   wb + 3 * 65536, bo,
                                                   g_ot, b_ot, g1, b1, g2, b2,
                                                   S, vt, (float*)d_out);
}